// Round 1
// baseline (2409.734 us; speedup 1.0000x reference)
//
#include <hip/hip_runtime.h>

#define BB 1024
#define TT 512
#define HH 64
#define GG 256  // 4*H

__device__ __forceinline__ float sigmoidf_(float v) {
    return 1.0f / (1.0f + __expf(-v));
}
__device__ __forceinline__ float tanhf_(float v) {
    // tanh(x) = 2*sigmoid(2x) - 1  (safe: no inf/inf)
    return fmaf(2.0f, sigmoidf_(2.0f * v), -1.0f);
}

__global__ __launch_bounds__(256, 2)
void lstm_fused(const float* __restrict__ x,     // [B,T] (I=1)
                const float* __restrict__ Wih0,  // [256]
                const float* __restrict__ Whh0,  // [256,64]
                const float* __restrict__ bih0,  // [256]
                const float* __restrict__ bhh0,  // [256]
                const float* __restrict__ Wih1,  // [256,64]
                const float* __restrict__ Whh1,  // [256,64]
                const float* __restrict__ bih1,  // [256]
                const float* __restrict__ bhh1,  // [256]
                const float* __restrict__ Wfc,   // [64]
                const float* __restrict__ bfc,   // [1]
                float* __restrict__ out)         // [B]
{
    __shared__ float s_x[TT];
    __shared__ float s_h0[HH];
    __shared__ float s_h1[HH];
    __shared__ float s_g0[GG];
    __shared__ float s_g1[GG];

    const int g = threadIdx.x;   // gate row 0..255
    const int b = blockIdx.x;    // batch element

    // ---- one-time: per-thread constants + weight rows into registers ----
    const float xw0   = Wih0[g];
    const float bias0 = bih0[g] + bhh0[g];
    const float bias1 = bih1[g] + bhh1[g];

    float4 w0[16], wi1[16], w1[16];
    {
        const float4* p0 = (const float4*)(Whh0 + g * HH);
        const float4* p1 = (const float4*)(Wih1 + g * HH);
        const float4* p2 = (const float4*)(Whh1 + g * HH);
#pragma unroll
        for (int i = 0; i < 16; ++i) {
            w0[i]  = p0[i];
            wi1[i] = p1[i];
            w1[i]  = p2[i];
        }
    }

    // stage x row for this batch element (coalesced)
    s_x[g]       = x[b * TT + g];
    s_x[g + 256] = x[b * TT + 256 + g];

    // zero initial hidden state
    if (g < HH) { s_h0[g] = 0.0f; s_h1[g] = 0.0f; }

    float c0 = 0.0f;  // live in threads [0,64)
    float c1 = 0.0f;  // live in threads [64,128)

    __syncthreads();

    for (int t = 0; t < TT; ++t) {
        // ---- phase 1: gates0 = x-term + Whh0.h0 ; acc1 = bias1 + Whh1.h1 ----
        float acc0 = fmaf(xw0, s_x[t], bias0);
        float acc1 = bias1;
        {
            const float4* h0v = (const float4*)s_h0;
            const float4* h1v = (const float4*)s_h1;
#pragma unroll
            for (int i = 0; i < 16; ++i) {
                float4 a = h0v[i];
                float4 bq = h1v[i];
                acc0 = fmaf(w0[i].x, a.x, acc0);
                acc0 = fmaf(w0[i].y, a.y, acc0);
                acc0 = fmaf(w0[i].z, a.z, acc0);
                acc0 = fmaf(w0[i].w, a.w, acc0);
                acc1 = fmaf(w1[i].x, bq.x, acc1);
                acc1 = fmaf(w1[i].y, bq.y, acc1);
                acc1 = fmaf(w1[i].z, bq.z, acc1);
                acc1 = fmaf(w1[i].w, bq.w, acc1);
            }
        }
        s_g0[g] = acc0;
        __syncthreads();

        // ---- phase 2: layer-0 unit update (threads 0..63) ----
        if (g < HH) {
            float gi = s_g0[g];
            float gf = s_g0[g + 64];
            float gg = s_g0[g + 128];
            float go = s_g0[g + 192];
            float i_ = sigmoidf_(gi);
            float f_ = sigmoidf_(gf);
            float g_ = tanhf_(gg);
            float o_ = sigmoidf_(go);
            c0 = fmaf(f_, c0, i_ * g_);
            s_h0[g] = o_ * tanhf_(c0);
        }
        __syncthreads();

        // ---- phase 3: acc1 += Wih1.h0_new ----
        {
            const float4* h0v = (const float4*)s_h0;
#pragma unroll
            for (int i = 0; i < 16; ++i) {
                float4 a = h0v[i];
                acc1 = fmaf(wi1[i].x, a.x, acc1);
                acc1 = fmaf(wi1[i].y, a.y, acc1);
                acc1 = fmaf(wi1[i].z, a.z, acc1);
                acc1 = fmaf(wi1[i].w, a.w, acc1);
            }
        }
        s_g1[g] = acc1;
        __syncthreads();

        // ---- phase 4: layer-1 unit update (threads 64..127) ----
        if (g >= 64 && g < 128) {
            int j = g - 64;
            float gi = s_g1[j];
            float gf = s_g1[j + 64];
            float gg = s_g1[j + 128];
            float go = s_g1[j + 192];
            float i_ = sigmoidf_(gi);
            float f_ = sigmoidf_(gf);
            float g_ = tanhf_(gg);
            float o_ = sigmoidf_(go);
            c1 = fmaf(f_, c1, i_ * g_);
            s_h1[j] = o_ * tanhf_(c1);
        }
        __syncthreads();
    }

    // ---- epilogue: out[b] = h1_last . Wfc + bfc ----
    if (g < HH) {
        float v = s_h1[g] * Wfc[g];
#pragma unroll
        for (int off = 32; off > 0; off >>= 1) {
            v += __shfl_down(v, off);
        }
        if (g == 0) out[b] = v + bfc[0];
    }
}

extern "C" void kernel_launch(void* const* d_in, const int* in_sizes, int n_in,
                              void* d_out, int out_size, void* d_ws, size_t ws_size,
                              hipStream_t stream) {
    const float* x    = (const float*)d_in[0];
    const float* Wih0 = (const float*)d_in[1];
    const float* Whh0 = (const float*)d_in[2];
    const float* bih0 = (const float*)d_in[3];
    const float* bhh0 = (const float*)d_in[4];
    const float* Wih1 = (const float*)d_in[5];
    const float* Whh1 = (const float*)d_in[6];
    const float* bih1 = (const float*)d_in[7];
    const float* bhh1 = (const float*)d_in[8];
    const float* Wfc  = (const float*)d_in[9];
    const float* bfc  = (const float*)d_in[10];
    float* out = (float*)d_out;

    lstm_fused<<<dim3(BB), dim3(256), 0, stream>>>(
        x, Wih0, Whh0, bih0, bhh0, Wih1, Whh1, bih1, bhh1, Wfc, bfc, out);
}

// Round 2
// 938.909 us; speedup vs baseline: 2.5665x; 2.5665x over previous
//
#include <hip/hip_runtime.h>

#define BB 1024
#define TT 512
#define HH 64
#define NB 2   // batch elements per block

__device__ __forceinline__ float sigmoidf_(float v) {
    return 1.0f / (1.0f + __expf(-v));
}
__device__ __forceinline__ float tanhf_(float v) {
    // tanh(x) = 2*sigmoid(2x) - 1  (safe: no inf/inf)
    return fmaf(2.0f, sigmoidf_(2.0f * v), -1.0f);
}

// Layer-pipelined fused LSTM: at iteration s, layer 0 computes timestep s
// while layer 1 computes timestep s-1. Both gate matvecs become one phase;
// 2 barriers per iteration instead of 4, and the unit-update phase uses all
// 256 threads (NB=2 batches x 2 layers x 64 units).
__global__ __launch_bounds__(256, 2)
void lstm_fused2(const float* __restrict__ x,     // [B,T] (I=1)
                 const float* __restrict__ Wih0,  // [256]
                 const float* __restrict__ Whh0,  // [256,64]
                 const float* __restrict__ bih0,  // [256]
                 const float* __restrict__ bhh0,  // [256]
                 const float* __restrict__ Wih1,  // [256,64]
                 const float* __restrict__ Whh1,  // [256,64]
                 const float* __restrict__ bih1,  // [256]
                 const float* __restrict__ bhh1,  // [256]
                 const float* __restrict__ Wfc,   // [64]
                 const float* __restrict__ bfc,   // [1]
                 float* __restrict__ out)         // [B]
{
    __shared__ float s_x[NB][TT];
    __shared__ float s_h0[NB][HH];
    __shared__ float s_h1[NB][HH];
    __shared__ float s_g0[NB][256];
    __shared__ float s_g1[NB][256];

    const int g  = threadIdx.x;        // gate row 0..255
    const int b0 = blockIdx.x * NB;    // first batch element of this block

    // ---- one-time: per-thread constants + weight rows into registers ----
    const float xw0   = Wih0[g];
    const float bias0 = bih0[g] + bhh0[g];
    const float bias1 = bih1[g] + bhh1[g];

    float4 w0[16], wi1[16], w1[16];
    {
        const float4* p0 = (const float4*)(Whh0 + g * HH);
        const float4* p1 = (const float4*)(Wih1 + g * HH);
        const float4* p2 = (const float4*)(Whh1 + g * HH);
#pragma unroll
        for (int i = 0; i < 16; ++i) {
            w0[i]  = p0[i];
            wi1[i] = p1[i];
            w1[i]  = p2[i];
        }
    }

    // stage x rows for this block's NB batch elements (coalesced)
#pragma unroll
    for (int k = 0; k < (NB * TT) / 256; ++k) {
        int idx = g + 256 * k;
        int nb  = idx >> 9;      // / TT
        int pos = idx & (TT - 1);
        s_x[nb][pos] = x[(b0 + nb) * TT + pos];
    }

    // zero initial hidden state (NB*HH = 128 floats per array)
    if (g < NB * HH) {
        (&s_h0[0][0])[g] = 0.0f;
        (&s_h1[0][0])[g] = 0.0f;
    }

    // cell state residency: tid<128 -> layer0 (nb=tid>>6, j=tid&63)
    //                       tid>=128 -> layer1 (nb=(tid>>6)&1, j=tid&63)
    float cst = 0.0f;

    __syncthreads();

    for (int s = 0; s <= TT; ++s) {
        // ---- phase 1 (all 256 threads, both layers, NB batches) ----
        // layer0 gates for timestep s (uses h0[s-1]);
        // layer1 gates for timestep s-1 (uses h1[s-2] and h0[s-1]).
        {
            const int xs = (s < TT) ? s : (TT - 1);  // s==TT result discarded
            float acc0[NB], a1h[NB], a1x[NB];
#pragma unroll
            for (int nb = 0; nb < NB; ++nb) {
                acc0[nb] = fmaf(xw0, s_x[nb][xs], bias0);
                a1h[nb]  = bias1;
                a1x[nb]  = 0.0f;
            }
#pragma unroll
            for (int i = 0; i < 16; ++i) {
#pragma unroll
                for (int nb = 0; nb < NB; ++nb) {
                    const float4 h0q = ((const float4*)s_h0[nb])[i];
                    const float4 h1q = ((const float4*)s_h1[nb])[i];
                    acc0[nb] = fmaf(w0[i].x,  h0q.x, acc0[nb]);
                    acc0[nb] = fmaf(w0[i].y,  h0q.y, acc0[nb]);
                    acc0[nb] = fmaf(w0[i].z,  h0q.z, acc0[nb]);
                    acc0[nb] = fmaf(w0[i].w,  h0q.w, acc0[nb]);
                    a1x[nb]  = fmaf(wi1[i].x, h0q.x, a1x[nb]);
                    a1x[nb]  = fmaf(wi1[i].y, h0q.y, a1x[nb]);
                    a1x[nb]  = fmaf(wi1[i].z, h0q.z, a1x[nb]);
                    a1x[nb]  = fmaf(wi1[i].w, h0q.w, a1x[nb]);
                    a1h[nb]  = fmaf(w1[i].x,  h1q.x, a1h[nb]);
                    a1h[nb]  = fmaf(w1[i].y,  h1q.y, a1h[nb]);
                    a1h[nb]  = fmaf(w1[i].z,  h1q.z, a1h[nb]);
                    a1h[nb]  = fmaf(w1[i].w,  h1q.w, a1h[nb]);
                }
            }
#pragma unroll
            for (int nb = 0; nb < NB; ++nb) {
                s_g0[nb][g] = acc0[nb];
                s_g1[nb][g] = a1h[nb] + a1x[nb];
            }
        }
        __syncthreads();

        // ---- phase 2: unit updates, all 256 threads ----
        if (g < 128) {
            // layer 0, timestep s (skip at s==TT)
            if (s < TT) {
                const int nb = g >> 6;
                const int j  = g & 63;
                float gi = s_g0[nb][j];
                float gf = s_g0[nb][j + 64];
                float gg = s_g0[nb][j + 128];
                float go = s_g0[nb][j + 192];
                float i_ = sigmoidf_(gi);
                float f_ = sigmoidf_(gf);
                float g_ = tanhf_(gg);
                float o_ = sigmoidf_(go);
                cst = fmaf(f_, cst, i_ * g_);
                s_h0[nb][j] = o_ * tanhf_(cst);
            }
        } else {
            // layer 1, timestep s-1 (skip at s==0)
            if (s >= 1) {
                const int nb = (g >> 6) & 1;
                const int j  = g & 63;
                float gi = s_g1[nb][j];
                float gf = s_g1[nb][j + 64];
                float gg = s_g1[nb][j + 128];
                float go = s_g1[nb][j + 192];
                float i_ = sigmoidf_(gi);
                float f_ = sigmoidf_(gf);
                float g_ = tanhf_(gg);
                float o_ = sigmoidf_(go);
                cst = fmaf(f_, cst, i_ * g_);
                s_h1[nb][j] = o_ * tanhf_(cst);
            }
        }
        __syncthreads();
    }

    // ---- epilogue: out[b0+nb] = h1_last . Wfc + bfc ----
    if (g < NB * HH) {
        const int nb = g >> 6;
        const int j  = g & 63;
        float v = s_h1[nb][j] * Wfc[j];
#pragma unroll
        for (int off = 32; off > 0; off >>= 1) {
            v += __shfl_down(v, off);
        }
        if (j == 0) out[b0 + nb] = v + bfc[0];
    }
}

extern "C" void kernel_launch(void* const* d_in, const int* in_sizes, int n_in,
                              void* d_out, int out_size, void* d_ws, size_t ws_size,
                              hipStream_t stream) {
    const float* x    = (const float*)d_in[0];
    const float* Wih0 = (const float*)d_in[1];
    const float* Whh0 = (const float*)d_in[2];
    const float* bih0 = (const float*)d_in[3];
    const float* bhh0 = (const float*)d_in[4];
    const float* Wih1 = (const float*)d_in[5];
    const float* Whh1 = (const float*)d_in[6];
    const float* bih1 = (const float*)d_in[7];
    const float* bhh1 = (const float*)d_in[8];
    const float* Wfc  = (const float*)d_in[9];
    const float* bfc  = (const float*)d_in[10];
    float* out = (float*)d_out;

    lstm_fused2<<<dim3(BB / NB), dim3(256), 0, stream>>>(
        x, Wih0, Whh0, bih0, bhh0, Wih1, Whh1, bih1, bhh1, Wfc, bfc, out);
}